// Round 10
// baseline (455.968 us; speedup 1.0000x reference)
//
#include <hip/hip_runtime.h>

#define N_TOK 8192
#define DIM   2048
#define HID   2048
#define NE    8
#define NKT   (DIM / 64)

typedef unsigned short u16;
typedef __attribute__((ext_vector_type(4))) float f4v;
typedef __attribute__((ext_vector_type(8))) short s8v;

__device__ __forceinline__ unsigned int cvtpk(float lo, float hi) {
  unsigned int r;
  asm volatile("v_cvt_pk_bf16_f32 %0, %1, %2" : "=v"(r) : "v"(lo), "v"(hi));
  return r;
}

// ---------------- gating: logits -> softmax -> top2 (NO atomics) ----------------
__global__ __launch_bounds__(256) void gating_kernel(
    const float* __restrict__ x, const float* __restrict__ Wg,
    const float* __restrict__ bg, int* __restrict__ sel,
    float* __restrict__ wslot)
{
  __shared__ float wg_lds[NE][DIM];   // 64 KB
  #pragma unroll
  for (int i = 0; i < 16; ++i) {
    int f = threadIdx.x + 256 * i;          // float4 index 0..4095
    int d = f >> 1, ep = (f & 1) * 4;
    float4 w = reinterpret_cast<const float4*>(Wg)[f];
    wg_lds[ep + 0][d] = w.x; wg_lds[ep + 1][d] = w.y;
    wg_lds[ep + 2][d] = w.z; wg_lds[ep + 3][d] = w.w;
  }
  __syncthreads();

  int wave = threadIdx.x >> 6, lane = threadIdx.x & 63;
  #pragma unroll 2
  for (int j = 0; j < 4; ++j) {
    int n = blockIdx.x * 16 + wave * 4 + j;
    const float4* x4 = reinterpret_cast<const float4*>(x + (size_t)n * DIM);
    float acc[NE] = {0.f,0.f,0.f,0.f,0.f,0.f,0.f,0.f};
    #pragma unroll
    for (int i = 0; i < 8; ++i) {
      int d4 = lane + 64 * i;
      float4 xv = x4[d4];
      #pragma unroll
      for (int e = 0; e < NE; ++e) {
        float4 w = *reinterpret_cast<const float4*>(&wg_lds[e][d4 * 4]);
        acc[e] += xv.x * w.x + xv.y * w.y + xv.z * w.z + xv.w * w.w;
      }
    }
    #pragma unroll
    for (int e = 0; e < NE; ++e)
      #pragma unroll
      for (int off = 32; off; off >>= 1)
        acc[e] += __shfl_xor(acc[e], off);

    if (lane == 0) {
      float m = -1e30f;
      #pragma unroll
      for (int e = 0; e < NE; ++e) { acc[e] += bg[e]; m = fmaxf(m, acc[e]); }
      float p[NE]; float s = 0.f;
      #pragma unroll
      for (int e = 0; e < NE; ++e) { p[e] = expf(acc[e] - m); s += p[e]; }
      float inv = 1.0f / s;
      int e1 = 0; float v1 = p[0];
      #pragma unroll
      for (int e = 1; e < NE; ++e) if (p[e] > v1) { v1 = p[e]; e1 = e; }
      int e2 = -1; float v2 = -1.f;
      #pragma unroll
      for (int e = 0; e < NE; ++e) if (e != e1 && p[e] > v2) { v2 = p[e]; e2 = e; }
      sel[n] = e1 | (e2 << 4);
      wslot[n] = v1 * inv;
      wslot[N_TOK + n] = v2 * inv;
    }
  }
}

// ---------------- build per-(slot,expert) token lists: deterministic compaction ----------------
__global__ __launch_bounds__(256) void build_lists_kernel(
    const int* __restrict__ sel, int* __restrict__ counts, int* __restrict__ lists)
{
  __shared__ int wsum[4];
  __shared__ int runbase;
  int b = blockIdx.x;           // 0..15: slot = b>>3, expert = b&7
  int s = b >> 3, e = b & 7;
  int t = threadIdx.x, lane = t & 63, wave = t >> 6;
  if (t == 0) runbase = 0;
  __syncthreads();
  int* listp = lists + (size_t)b * N_TOK;
  for (int base = 0; base < N_TOK; base += 256) {
    int n = base + t;
    int sv = sel[n];
    int field = s ? (sv >> 4) : (sv & 15);
    bool p = (field == e);
    unsigned long long mask = __ballot(p);
    int rank = __popcll(mask & ((1ull << lane) - 1ull));
    int wtot = __popcll(mask);
    if (lane == 0) wsum[wave] = wtot;
    __syncthreads();
    int wbase = 0;
    #pragma unroll
    for (int w = 0; w < 4; ++w) wbase += (w < wave) ? wsum[w] : 0;
    int tot = wsum[0] + wsum[1] + wsum[2] + wsum[3];
    if (p) listp[runbase + wbase + rank] = n;
    __syncthreads();
    if (t == 0) runbase += tot;
    __syncthreads();
  }
  if (t == 0) counts[b] = runbase;
}

// ---------------- build compact tile descriptors ----------------
__global__ void build_desc_kernel(const int* __restrict__ counts,
                                  int* __restrict__ gfirst, int* __restrict__ desc)
{
  if (threadIdx.x == 0 && blockIdx.x == 0) {
    for (int s = 0; s < 2; ++s) {
      int tc = 0;
      for (int e = 0; e < NE; ++e) {
        gfirst[s * 9 + e] = tc;
        int nt = (counts[s * NE + e] + 127) >> 7;
        for (int i = 0; i < nt; ++i) desc[s * 71 + tc++] = (e << 8) | i;
      }
      gfirst[s * 9 + 8] = tc;
    }
  }
}

// ---------------- GEMM: R8 sharding + dual-stage register pipeline ----------------
// 16 waves, each owns a 32x32 sub-tile (acc 16 VGPR). Per kt per thread:
// A 2x float4, B 8x scalar. Two named stage sets (S0/S1) alternate; the WRITE of
// one stage waits only its own loads (counted vmcnt by issue order), the other
// stage stays in flight across barrier+mma -> ~2x outstanding loads/wave.
template <int PHASE>
__global__ __launch_bounds__(1024, 4) void moe_gemm_f32(
    const float* __restrict__ xf, const float* __restrict__ Wef,
    const float* __restrict__ be, const int* __restrict__ counts,
    const int* __restrict__ gfirst, const int* __restrict__ desc,
    const int* __restrict__ lists, const float* __restrict__ wslot,
    float* __restrict__ out)
{
  __shared__ __align__(16) u16 A_lds[128 * 64];   // bf16 [m][k], XOR-swizzled rows
  __shared__ __align__(16) u16 B_lds[128 * 64];   // bf16 [n][k], XOR-swizzled rows
  __shared__ int   tok_lds[128];
  __shared__ float wgt_lds[128];

  const int ntile = blockIdx.x;          // 0..15 (fastest: L2 locality)
  const int idx   = blockIdx.y;          // 0..70
  if (idx >= gfirst[PHASE * 9 + 8]) return;
  const int d  = desc[PHASE * 71 + idx];
  const int e  = d >> 8;
  const int mt = d & 255;
  const int cnt = counts[PHASE * NE + e];

  const int t = threadIdx.x;
  if (t < 128) {
    int r = mt * 128 + t;
    int rc = (r < cnt) ? r : (cnt - 1);
    int tok = lists[(PHASE * NE + e) * N_TOK + rc];
    tok_lds[t] = tok;
    wgt_lds[t] = wslot[PHASE * N_TOK + tok];
  }
  __syncthreads();

  const int lane = t & 63, wid = t >> 6;        // wid 0..15
  const int wm = (wid & 3) * 32, wn = (wid >> 2) * 32;

  f4v acc[2][2];
  f4v zero = {0.f, 0.f, 0.f, 0.f};
  #pragma unroll
  for (int mi = 0; mi < 2; ++mi)
    #pragma unroll
    for (int ni = 0; ni < 2; ++ni) acc[mi][ni] = zero;

  const float* wef = Wef + (size_t)e * DIM * HID;

  // A: 2 float4 per thread
  const float* ap[2]; unsigned int ab[2];
  #pragma unroll
  for (int i = 0; i < 2; ++i) {
    int flat = t + 1024 * i;
    int row = flat >> 4, c4 = flat & 15;
    ap[i] = xf + (size_t)tok_lds[row] * DIM + c4 * 4;
    ab[i] = ((unsigned int)(row * 128 + c4 * 8)) ^ (((unsigned int)row & 7u) << 4);
  }
  // B: 8 scalar column loads per thread
  const int bn = t & 127, bh = t >> 7;          // bh 0..7
  const float* bp0 = wef + (size_t)(bh * 8) * HID + ntile * 128 + bn;
  const unsigned int bbyte = ((unsigned int)(bn * 128 + bh * 16)) ^ (((unsigned int)bn & 7u) << 4);

  const int lrow = lane & 15, lkg = lane >> 4;

  // --- named stage sets (static indexing, rule #20) ---
  float4 sa0_0, sa0_1; float sb0[8];
  float4 sa1_0, sa1_1; float sb1[8];

#define ISSUE0(KT) do {                                                         \
    sa0_0 = *reinterpret_cast<const float4*>(ap[0] + (KT) * 64);                \
    sa0_1 = *reinterpret_cast<const float4*>(ap[1] + (KT) * 64);                \
    const float* bpk = bp0 + (size_t)(KT) * 64 * HID;                           \
    _Pragma("unroll") for (int j = 0; j < 8; ++j) sb0[j] = bpk[(size_t)j * HID];\
  } while (0)
#define ISSUE1(KT) do {                                                         \
    sa1_0 = *reinterpret_cast<const float4*>(ap[0] + (KT) * 64);                \
    sa1_1 = *reinterpret_cast<const float4*>(ap[1] + (KT) * 64);                \
    const float* bpk = bp0 + (size_t)(KT) * 64 * HID;                           \
    _Pragma("unroll") for (int j = 0; j < 8; ++j) sb1[j] = bpk[(size_t)j * HID];\
  } while (0)
#define WRITE_SET(A0, A1, B) do {                                               \
    uint2 w0; w0.x = cvtpk(A0.x, A0.y); w0.y = cvtpk(A0.z, A0.w);               \
    *reinterpret_cast<uint2*>(reinterpret_cast<char*>(A_lds) + ab[0]) = w0;     \
    uint2 w1; w1.x = cvtpk(A1.x, A1.y); w1.y = cvtpk(A1.z, A1.w);               \
    *reinterpret_cast<uint2*>(reinterpret_cast<char*>(A_lds) + ab[1]) = w1;     \
    union { unsigned int w[4]; s8v v; } ub;                                     \
    ub.w[0] = cvtpk(B[0], B[1]); ub.w[1] = cvtpk(B[2], B[3]);                   \
    ub.w[2] = cvtpk(B[4], B[5]); ub.w[3] = cvtpk(B[6], B[7]);                   \
    *reinterpret_cast<s8v*>(reinterpret_cast<char*>(B_lds) + bbyte) = ub.v;     \
  } while (0)
#define MMA_STEP() do {                                                         \
    _Pragma("unroll") for (int kk2 = 0; kk2 < 2; ++kk2) {                       \
      s8v a[2], b[2];                                                           \
      unsigned int koff = (unsigned int)(kk2 * 64 + lkg * 16);                  \
      _Pragma("unroll") for (int i = 0; i < 2; ++i) {                           \
        unsigned int arow = (unsigned int)(wm + i * 16 + lrow);                 \
        a[i] = *reinterpret_cast<const s8v*>(reinterpret_cast<const char*>(A_lds)\
               + ((arow * 128u + koff) ^ ((arow & 7u) << 4)));                  \
        unsigned int brow = (unsigned int)(wn + i * 16 + lrow);                 \
        b[i] = *reinterpret_cast<const s8v*>(reinterpret_cast<const char*>(B_lds)\
               + ((brow * 128u + koff) ^ ((brow & 7u) << 4)));                  \
      }                                                                         \
      _Pragma("unroll") for (int mi = 0; mi < 2; ++mi)                          \
        _Pragma("unroll") for (int ni = 0; ni < 2; ++ni)                        \
          acc[mi][ni] = __builtin_amdgcn_mfma_f32_16x16x32_bf16(                \
              a[mi], b[ni], acc[mi][ni], 0, 0, 0);                              \
    }                                                                           \
  } while (0)

  ISSUE0(0);
  ISSUE1(1);

  #pragma unroll 1
  for (int kt = 0; kt < NKT; kt += 2) {
    // --- even kt: stage S0 ---
    WRITE_SET(sa0_0, sa0_1, sb0);       // waits vmcnt for S0 only (S1 in flight)
    __syncthreads();
    if (kt + 2 < NKT) ISSUE0(kt + 2);   // refill S0: in flight across mma+bar+odd step
    MMA_STEP();
    __syncthreads();
    // --- odd kt+1: stage S1 ---
    WRITE_SET(sa1_0, sa1_1, sb1);       // waits vmcnt for S1 only (S0 in flight)
    __syncthreads();
    if (kt + 3 < NKT) ISSUE1(kt + 3);   // refill S1
    MMA_STEP();
    __syncthreads();
  }

#undef ISSUE0
#undef ISSUE1
#undef WRITE_SET
#undef MMA_STEP

  // epilogue: D row=(lane>>4)*4+q (A/m), col=lane&15 (B/n)  [m89-verified]
  const float* bev = be + (size_t)e * HID + ntile * 128;
  #pragma unroll
  for (int ni = 0; ni < 2; ++ni) {
    int col = wn + ni * 16 + (lane & 15);
    float bevv = bev[col];
    #pragma unroll
    for (int mi = 0; mi < 2; ++mi) {
      #pragma unroll
      for (int q = 0; q < 4; ++q) {
        int row = wm + mi * 16 + (lane >> 4) * 4 + q;
        if (mt * 128 + row < cnt) {
          int tok = tok_lds[row];
          float w = wgt_lds[row];
          float v = w * (acc[mi][ni][q] + bevv);
          float* o = out + (size_t)tok * HID + ntile * 128 + col;
          if (PHASE == 0) *o = v; else *o += v;
        }
      }
    }
  }
}

// ---------------- host ----------------
extern "C" void kernel_launch(void* const* d_in, const int* in_sizes, int n_in,
                              void* d_out, int out_size, void* d_ws, size_t ws_size,
                              hipStream_t stream) {
  const float* x  = (const float*)d_in[0];
  const float* Wg = (const float*)d_in[1];
  const float* bg = (const float*)d_in[2];
  const float* We = (const float*)d_in[3];
  const float* be = (const float*)d_in[4];
  float* out = (float*)d_out;
  char* ws = (char*)d_ws;

  int*   counts = (int*)ws;                         // 16 ints @0
  int*   gfirst = (int*)(ws + 64);                  // 18 ints
  int*   desc   = (int*)(ws + 256);                 // 142 ints
  int*   sel    = (int*)(ws + 1024);                // 8192 ints
  float* wslot  = (float*)(ws + 33792);             // 16384 f32
  int*   lists  = (int*)(ws + 99328);               // 2*8*8192 ints -> end 623616

  hipLaunchKernelGGL(gating_kernel, dim3(512), dim3(256), 0, stream,
                     x, Wg, bg, sel, wslot);
  hipLaunchKernelGGL(build_lists_kernel, dim3(16), dim3(256), 0, stream,
                     sel, counts, lists);
  hipLaunchKernelGGL(build_desc_kernel, dim3(1), dim3(64), 0, stream,
                     counts, gfirst, desc);

  dim3 ggrid(16, 71);   // x = ntile fastest: L2 locality
  hipLaunchKernelGGL((moe_gemm_f32<0>), ggrid, dim3(1024), 0, stream,
                     x, We, be, counts, gfirst, desc, lists, wslot, out);
  hipLaunchKernelGGL((moe_gemm_f32<1>), ggrid, dim3(1024), 0, stream,
                     x, We, be, counts, gfirst, desc, lists, wslot, out);
}